// Round 12
// baseline (174.612 us; speedup 1.0000x reference)
//
#include <hip/hip_runtime.h>
#include <hip/hip_bf16.h>
#include <math.h>

typedef __hip_bfloat16  bf16;
typedef __hip_bfloat162 bf162;
typedef __attribute__((ext_vector_type(8))) short short8;   // 8 bf16 (MFMA A/B frag)
typedef __attribute__((ext_vector_type(4))) float f32x4;    // MFMA C/D frag

#define BB   2
#define CINC 64
#define NN   1024
#define SSS  32
#define NS   (NN * SSS)

// ---- workspace layout (float offsets) ----
#define OFF_WE21 0        // f32 [o=128][c=64] (prep1/2); prep3 REUSES as WKA/wwr
#define OFF_WR   8192     // f32 [128]
#define OFF_KBA  8320     // bf16 [i=128][c2=128]: c2<64 -> Wk2 ; c2>=64 -> -Wq2
#define OFF_VB   16512    // bf16 [i=128][c=64]
#define OFF_F1B  20608    // bf16 [o=128][kappa=384], kappa=kk*128+i
#define OFF_F2B  45184    // bf16 [o=128][c=128]
// prep3 outputs: WKA bf16 [16][128] at OFF_WE21 ; wwr f32[3] at OFF_WE21+1024
#define WS_FLAG_IDX 2000
#define WS_MAGIC    0x5A17C0DEu
#define WS_NEED_FLOATS 53376

// ---- shared memory (BYTE offsets) ---- (40128 B, 4 blocks/CU)
#define S_ATT_B  0        // 26112 B
#define S_RED_B  18944    // f32[384] inside s_att free region
#define S_FTS_B  26112    // 96*72*2 = 13824 B (full tile staged in PROLOGUE)
#define S_XYZ_B  39936    // bf16[96] = 192 B
#define SMEM_BYTES 40128

// Light barrier (R11, measured -1.5%): barriers here guard LDS only, so wait
// lgkmcnt, not vmcnt -> pre-barrier GLOBAL loads stay in flight across it.
#define LBAR() do {                                         \
    asm volatile("s_waitcnt lgkmcnt(0)" ::: "memory");      \
    __builtin_amdgcn_s_barrier();                           \
    asm volatile("" ::: "memory");                          \
    __builtin_amdgcn_sched_barrier(0);                      \
} while (0)

__device__ __forceinline__ float bf2f(short s) {
    unsigned int u = ((unsigned int)(unsigned short)s) << 16;
    return __uint_as_float(u);
}
__device__ __forceinline__ short f2bf(float f) {
    bf16 h = __float2bfloat16(f);
    return *reinterpret_cast<short*>(&h);
}
__device__ __forceinline__ unsigned pk2(float a, float b) {
    bf162 p = __float22bfloat162_rn(make_float2(a, b));
    return *reinterpret_cast<unsigned*>(&p);
}
__device__ __forceinline__ bool prep_done(const float* ws) {
    return *(const volatile unsigned*)((const unsigned*)ws + WS_FLAG_IDX) == WS_MAGIC;
}

// ---------- prep kernel 1: We21 = W_e2 @ W_e1 ----------
__global__ __launch_bounds__(256) void prep1(const float* __restrict__ We1,
                                             const float* __restrict__ We2,
                                             float* __restrict__ ws) {
    if (prep_done(ws)) return;
    int e = blockIdx.x * 256 + threadIdx.x;   // 8192 entries, grid = 32
    int o = e >> 6, c = e & 63;
    float acc = 0.f;
    for (int m = 0; m < 128; ++m)
        acc = fmaf(We2[o * 128 + m], We1[m * 64 + c], acc);
    ws[OFF_WE21 + o * 64 + c] = acc;
}

// ---------- prep kernel 2: fused weights (KBA aug / VB / WR / F1B / F2B) ----------
__global__ __launch_bounds__(256) void prep2(const float* __restrict__ Wq,
                                             const float* __restrict__ Wk,
                                             const float* __restrict__ Wv,
                                             const float* __restrict__ Wr1,
                                             const float* __restrict__ Wr2,
                                             const float* __restrict__ Wf1,
                                             const float* __restrict__ Wf2,
                                             float* __restrict__ ws) {
    if (prep_done(ws)) return;
    const float* we21 = ws + OFF_WE21;
    int e = blockIdx.x * 256 + threadIdx.x;
    if (e < 16384) {                           // KBA bf16 [i][c2=128]
        int i = e >> 7, c2 = e & 127;
        const float* W = (c2 < 64) ? Wk : Wq;
        int c = c2 & 63;
        float acc = 0.f;
        for (int o = 0; o < 128; ++o)
            acc = fmaf(W[i * 128 + o], we21[o * 64 + c], acc);
        if (c2 >= 64) acc = -acc;
        ((bf16*)(ws + OFF_KBA))[i * 128 + c2] = __float2bfloat16(acc);
    } else if (e < 24576) {                    // VB bf16 [i][c=64]
        int le = e - 16384;
        int i = le >> 6, c = le & 63;
        float acc = 0.f;
        for (int o = 0; o < 128; ++o)
            acc = fmaf(Wv[i * 128 + o], we21[o * 64 + c], acc);
        ((bf16*)(ws + OFF_VB))[i * 64 + c] = __float2bfloat16(acc);
    } else if (e < 24704) {                    // w_r f32
        int i = e - 24576;
        float acc = 0.f;
        for (int m = 0; m < 64; ++m)
            acc = fmaf(Wr2[i * 64 + m], Wr1[m], acc);
        ws[OFF_WR + i] = acc;
    } else if (e < 24704 + 49152) {            // F1B[o][kappa], kappa = kk*128+i
        int f = e - 24704;
        int o = f / 384, kp = f - o * 384;
        int c = (kp & 127) * 3 + (kp >> 7);
        ((bf16*)(ws + OFF_F1B))[f] = __float2bfloat16(Wf1[o * 384 + c]);
    } else if (e < 24704 + 49152 + 16384) {    // F2B[o][c]
        int f = e - (24704 + 49152);
        ((bf16*)(ws + OFF_F2B))[f] = __float2bfloat16(Wf2[f]);
    }
}

// ---------- prep kernel 3: WKA = Wstd @ KBA (bf16), wwr = Wstd @ w_r ----------
__global__ __launch_bounds__(256) void prep3(const float* __restrict__ Wstd,
                                             float* __restrict__ ws) {
    if (prep_done(ws)) return;
    int e = blockIdx.x * 256 + threadIdx.x;
    if (e < 2048) {                            // WKA bf16 [16][128], rows>=3 zero
        int j = e >> 7, c2 = e & 127;
        float acc = 0.f;
        if (j < 3) {
            const short* kba = (const short*)(ws + OFF_KBA);
            for (int i = 0; i < 128; ++i)
                acc = fmaf(Wstd[j * 128 + i], bf2f(kba[i * 128 + c2]), acc);
        }
        ((bf16*)(ws + OFF_WE21))[e] = __float2bfloat16(acc);
    } else if (e < 2051) {                     // wwr f32[3]
        int j = e - 2048;
        float acc = 0.f;
        for (int i = 0; i < 128; ++i)
            acc = fmaf(Wstd[j * 128 + i], ws[OFF_WR + i], acc);
        ws[OFF_WE21 + 1024 + j] = acc;
        if (j == 0) {
            __threadfence();
            *(volatile unsigned*)((unsigned*)ws + WS_FLAG_IDX) = WS_MAGIC;
        }
    }
}

// ---------- main fused kernel: one block per (b, n) ----------
// R12 = R11 + DEEPER cross-barrier prefetch (the only lever still paying):
//   (1) E prefetch 2->4 A-pairs (whole kk=0 quadrant)
//   (2) F prefetch 2->4 A-pairs (entire F A-operand; no post-barrier A loads)
//   (3) H's Va prefetched alongside F's frags (live across F, ~16 VGPR)
// VGPR was 56/128 cap -> headroom exists. Spill tripwire: WRITE_SIZE 3.07MB.
__global__ __launch_bounds__(256, 4) void fused_main(
        const float* __restrict__ gxyz, const float* __restrict__ gfts,
        const float* __restrict__ qxyz, const float* __restrict__ Wstd,
        const float* __restrict__ bf1,  const float* __restrict__ bf2,
        const float* __restrict__ ws,   float* __restrict__ out) {
    extern __shared__ char smc[];
    short* s_att  = (short*)(smc + S_ATT_B);   // att_t[(kk*32+s)][136]
    short* h_t    = s_att;                     // alias [32][136] (post-E)
    short* a_tt   = s_att + 4352;              // alias: a_tT[o=128][stride 40] post-F
    short* fts_s  = (short*)(smc + S_FTS_B);   // [96][72] full tile, live A..H
    short* s_xyzh = (short*)(smc + S_XYZ_B);   // bf16 xyz_rel[96]
    float* s_red  = (float*)(smc + S_RED_B);   // H-reduction scratch (own region)

    const int t    = threadIdx.x;
    // XCD swizzle: consecutive n on one XCD -> output write-combining in its L2
    const int bid0 = blockIdx.x;
    const int bid  = ((bid0 & 7) << 8) | (bid0 >> 3);   // bijective on 2048
    const int b    = bid >> 10;
    const int n    = bid & 1023;
    const int w    = t >> 6;        // wave id 0..3
    const int lane = t & 63;
    const int quad = lane >> 4;
    const int lq   = lane & 15;
    const int wb   = 32 * w;        // wave's i-base (B,H) / o-base (E,F)

    const float* gb = gfts + (size_t)b * (CINC * 3 * NS) + n * SSS;
    const short* kba = (const short*)(ws + OFF_KBA);
    const short* wka = (const short*)(ws + OFF_WE21);

    // staging geometry
    const int cp = t >> 3;              // c-pair 0..31
    const int ml = (t & 7) * 4;         // s base 0,4,...,28

    // ---------- persistent fragments: Ka + kq (h-invariant) + w_r + WKA ----------
    short8 Ka[2][2], Kq[2][2];
    #pragma unroll
    for (int it = 0; it < 2; ++it) {
        int i = wb + it * 16 + lq;
        Ka[it][0] = *(const short8*)(kba + i * 128 +  0 + quad * 8);
        Ka[it][1] = *(const short8*)(kba + i * 128 + 32 + quad * 8);
        Kq[it][0] = *(const short8*)(kba + i * 128 + 64 + quad * 8);
        Kq[it][1] = *(const short8*)(kba + i * 128 + 96 + quad * 8);
    }
    float4 wr2v[2] = { *(const float4*)(ws + OFF_WR + wb + quad * 4),
                       *(const float4*)(ws + OFF_WR + wb + 16 + quad * 4) };
    float wr2[2] = { ws[OFF_WR + wb + lq], ws[OFF_WR + wb + 16 + lq] };
    short8 WA[4];
    float wwr[3];
    if (w >= 2) {                       // only waves 2,3 compute z0
        #pragma unroll
        for (int kc = 0; kc < 4; ++kc)
            WA[kc] = *(const short8*)(wka + lq * 128 + kc * 32 + quad * 8);
        wwr[0] = ws[OFF_WE21 + 1024];
        wwr[1] = ws[OFF_WE21 + 1025];
        wwr[2] = ws[OFF_WE21 + 1026];
    }

    // ---------- PROLOGUE: stage ALL thirds (6 parallel float4 loads) + xyz ----------
    {
        float4 g0[3], g1[3];
        #pragma unroll
        for (int h = 0; h < 3; ++h) {
            const float* fb = gb + (2 * cp * 3 + h) * NS + ml;
            g0[h] = *(const float4*)(fb);
            g1[h] = *(const float4*)(fb + 3 * NS);
        }
        #pragma unroll
        for (int h = 0; h < 3; ++h) {
            short* dst = fts_s + (h * 32 + ml) * 72 + 2 * cp;
            *(unsigned*)(dst)       = pk2(g0[h].x, g1[h].x);
            *(unsigned*)(dst + 72)  = pk2(g0[h].y, g1[h].y);
            *(unsigned*)(dst + 144) = pk2(g0[h].z, g1[h].z);
            *(unsigned*)(dst + 216) = pk2(g0[h].w, g1[h].w);
        }
        if (t >= 160) {
            int id = t - 160;                // 0..95
            int d = id >> 5, s = id & 31;
            s_xyzh[id] = f2bf(gxyz[((b * NN + n) * SSS + s) * 3 + d]
                              - qxyz[(b * NN + n) * 3 + d]);
        }
    }
    LBAR();

    // ---------- Phase B: barrier-free (fts stable; att cols + z0 holes wave-owned) ----------
    #pragma unroll
    for (int h = 0; h < 3; ++h) {
        const short* qp = fts_s + (h * 32) * 72 + quad * 8;
        short8 aq0 = *(const short8*)(qp);
        short8 aq1 = *(const short8*)(qp + 32);

        // qv[it][reg] = -q[i] via swapped MFMA (B cols all = q row h*32)
        f32x4 qa[2];
        #pragma unroll
        for (int it = 0; it < 2; ++it) {
            f32x4 z = {0.f, 0.f, 0.f, 0.f};
            z = __builtin_amdgcn_mfma_f32_16x16x32_bf16(Kq[it][0], aq0, z, 0, 0, 0);
            z = __builtin_amdgcn_mfma_f32_16x16x32_bf16(Kq[it][1], aq1, z, 0, 0, 0);
            qa[it] = z;
        }
        #pragma unroll
        for (int mt_h = 0; mt_h < 2; ++mt_h) {
            int m = h * 32 + mt_h * 16 + lq;         // att row (= output col)
            const short* ap = fts_s + m * 72 + quad * 8;
            short8 a0 = *(const short8*)(ap);
            short8 a1 = *(const short8*)(ap + 32);
            float xm = bf2f(s_xyzh[m]);
            #pragma unroll
            for (int it = 0; it < 2; ++it) {
                f32x4 kk = {0.f, 0.f, 0.f, 0.f};
                kk = __builtin_amdgcn_mfma_f32_16x16x32_bf16(Ka[it][0], a0, kk, 0, 0, 0);
                kk = __builtin_amdgcn_mfma_f32_16x16x32_bf16(Ka[it][1], a1, kk, 0, 0, 0);
                float p[4];
                #pragma unroll
                for (int reg = 0; reg < 4; ++reg)
                    p[reg] = wr2v[it][reg] * xm - kk[reg] - qa[it][reg];
                uint2 pk;
                pk.x = pk2(p[0], p[1]);
                pk.y = pk2(p[2], p[3]);
                *(uint2*)(s_att + m * 136 + wb + it * 16 + quad * 4) = pk;
            }
            // z0[j][m] = xm*wwr[j] - sum_c WKA[j][c2]*(fts|ftsq)[c2]  (fused C)
            if (w == 2 + mt_h) {
                f32x4 z2 = {0.f, 0.f, 0.f, 0.f};
                z2 = __builtin_amdgcn_mfma_f32_16x16x32_bf16(WA[0], a0,  z2, 0, 0, 0);
                z2 = __builtin_amdgcn_mfma_f32_16x16x32_bf16(WA[1], a1,  z2, 0, 0, 0);
                z2 = __builtin_amdgcn_mfma_f32_16x16x32_bf16(WA[2], aq0, z2, 0, 0, 0);
                z2 = __builtin_amdgcn_mfma_f32_16x16x32_bf16(WA[3], aq1, z2, 0, 0, 0);
                if (quad == 0) {          // rows j = reg < 3 ; col m = this lane's m
                    float* hp = (float*)(fts_s + m * 72 + 64);
                    #pragma unroll
                    for (int reg = 0; reg < 3; ++reg)
                        hp[reg] = xm * wwr[reg] - z2[reg];
                }
            }
        }
    }
    LBAR();   // publishes att (all cols) + z0 holes

    // ---------- Phase D (wave-local i-cols): attn2[i][kk][s] = sum_j att*z0 ----------
    #pragma unroll
    for (int u2 = 0; u2 < 2; ++u2) {
        int item = u2 * 64 + lane;
        int s  = item & 31;
        int i0 = wb + (item >> 5) * 8;        // own wave's columns only
        float z[3][3];
        #pragma unroll
        for (int kk = 0; kk < 3; ++kk) {
            const float* hp = (const float*)(fts_s + (kk * 32 + s) * 72 + 64);
            #pragma unroll
            for (int j = 0; j < 3; ++j)
                z[j][kk] = hp[j];
        }
        float af[3][8];
        #pragma unroll
        for (int j = 0; j < 3; ++j) {
            short8 v8 = *(const short8*)(s_att + (j * 32 + s) * 136 + i0);
            #pragma unroll
            for (int x = 0; x < 8; ++x) af[j][x] = bf2f(v8[x]);
        }
        #pragma unroll
        for (int kk = 0; kk < 3; ++kk) {
            float q0, q1;
            uint4 o4;
            q0 = af[0][0] * z[0][kk] + af[1][0] * z[1][kk] + af[2][0] * z[2][kk];
            q1 = af[0][1] * z[0][kk] + af[1][1] * z[1][kk] + af[2][1] * z[2][kk];
            o4.x = pk2(q0, q1);
            q0 = af[0][2] * z[0][kk] + af[1][2] * z[1][kk] + af[2][2] * z[2][kk];
            q1 = af[0][3] * z[0][kk] + af[1][3] * z[1][kk] + af[2][3] * z[2][kk];
            o4.y = pk2(q0, q1);
            q0 = af[0][4] * z[0][kk] + af[1][4] * z[1][kk] + af[2][4] * z[2][kk];
            q1 = af[0][5] * z[0][kk] + af[1][5] * z[1][kk] + af[2][5] * z[2][kk];
            o4.z = pk2(q0, q1);
            q0 = af[0][6] * z[0][kk] + af[1][6] * z[1][kk] + af[2][6] * z[2][kk];
            q1 = af[0][7] * z[0][kk] + af[1][7] * z[1][kk] + af[2][7] * z[2][kk];
            o4.w = pk2(q0, q1);
            *(uint4*)(s_att + (kk * 32 + s) * 136 + i0) = o4;
        }
    }
    // Prefetch E's entire kk=0 quadrant (4 A-pairs) BEFORE the light barrier.
    const short* f1b  = (const short*)(ws + OFF_F1B);
    const short* eab0 = f1b + (wb + lq) * 384 + quad * 8;
    const short* eab1 = eab0 + 16 * 384;
    short8 ea0[4], ea1[4];
    #pragma unroll
    for (int ks = 0; ks < 4; ++ks) {
        ea0[ks] = *(const short8*)(eab0 + ks * 32);
        ea1[ks] = *(const short8*)(eab1 + ks * 32);
    }
    LBAR();

    // ---------- Phase E: h = relu(Wf1 @ attn2 + b_f1) via MFMA (M=128,N=32,K=384) ----------
    f32x4 eacc[2][2];
    {
        f32x4 zz = {0.f, 0.f, 0.f, 0.f};
        eacc[0][0] = zz; eacc[0][1] = zz; eacc[1][0] = zz; eacc[1][1] = zz;
        #pragma unroll
        for (int ks = 0; ks < 4; ++ks) {     // kk=0 quadrant, prefetched A
            const short* bp = s_att + ks * 32 + quad * 8;
            short8 b0 = *(const short8*)(bp + lq * 136);
            short8 b1 = *(const short8*)(bp + (lq + 16) * 136);
            eacc[0][0] = __builtin_amdgcn_mfma_f32_16x16x32_bf16(ea0[ks], b0, eacc[0][0], 0, 0, 0);
            eacc[0][1] = __builtin_amdgcn_mfma_f32_16x16x32_bf16(ea0[ks], b1, eacc[0][1], 0, 0, 0);
            eacc[1][0] = __builtin_amdgcn_mfma_f32_16x16x32_bf16(ea1[ks], b0, eacc[1][0], 0, 0, 0);
            eacc[1][1] = __builtin_amdgcn_mfma_f32_16x16x32_bf16(ea1[ks], b1, eacc[1][1], 0, 0, 0);
        }
        #pragma unroll 2
        for (int ks = 4; ks < 12; ++ks) {
            int kk = ks >> 2;
            int ic = (ks & 3) * 32 + quad * 8;
            short8 a0 = *(const short8*)(eab0 + ks * 32);
            short8 a1 = *(const short8*)(eab1 + ks * 32);
            const short* bp = s_att + (kk * 32) * 136 + ic;
            short8 b0 = *(const short8*)(bp + lq * 136);
            short8 b1 = *(const short8*)(bp + (lq + 16) * 136);
            eacc[0][0] = __builtin_amdgcn_mfma_f32_16x16x32_bf16(a0, b0, eacc[0][0], 0, 0, 0);
            eacc[0][1] = __builtin_amdgcn_mfma_f32_16x16x32_bf16(a0, b1, eacc[0][1], 0, 0, 0);
            eacc[1][0] = __builtin_amdgcn_mfma_f32_16x16x32_bf16(a1, b0, eacc[1][0], 0, 0, 0);
            eacc[1][1] = __builtin_amdgcn_mfma_f32_16x16x32_bf16(a1, b1, eacc[1][1], 0, 0, 0);
        }
    }
    LBAR();     // all attn2 reads complete before h_t overwrites it

    // E epilogue: h_t[s][o] (bf16), relu+bias
    #pragma unroll
    for (int mt = 0; mt < 2; ++mt) {
        int ob = wb + mt * 16 + quad * 4;
        float4 bb = *(const float4*)(bf1 + ob);
        float bv[4] = {bb.x, bb.y, bb.z, bb.w};
        #pragma unroll
        for (int nt = 0; nt < 2; ++nt) {
            f32x4 c = eacc[mt][nt];
            int s = nt * 16 + lq;
            uint2 pk;
            pk.x = pk2(fmaxf(c[0] + bv[0], 0.f), fmaxf(c[1] + bv[1], 0.f));
            pk.y = pk2(fmaxf(c[2] + bv[2], 0.f), fmaxf(c[3] + bv[3], 0.f));
            *(uint2*)(h_t + s * 136 + ob) = pk;
        }
    }
    // Prefetch F's ENTIRE A-frag set + H's Va BEFORE the light barrier.
    const short* f2b  = (const short*)(ws + OFF_F2B);
    const short* fab0 = f2b + (wb + lq) * 128 + quad * 8;
    const short* fab1 = fab0 + 16 * 128;
    short8 fa0[4], fa1[4];
    #pragma unroll
    for (int ks = 0; ks < 4; ++ks) {
        fa0[ks] = *(const short8*)(fab0 + ks * 32);
        fa1[ks] = *(const short8*)(fab1 + ks * 32);
    }
    short8 Va[2][2];
    {
        const short* vbb = (const short*)(ws + OFF_VB);
        #pragma unroll
        for (int it = 0; it < 2; ++it) {
            int i = wb + it * 16 + lq;
            Va[it][0] = *(const short8*)(vbb + i * 64 + quad * 8);
            Va[it][1] = *(const short8*)(vbb + i * 64 + 32 + quad * 8);
        }
    }
    LBAR();

    // ---------- Phase F: logits + FUSED SOFTMAX; store TRANSPOSED a_tT[o][40] ----------
    {
        f32x4 facc[2][2];
        f32x4 zz = {0.f, 0.f, 0.f, 0.f};
        facc[0][0] = zz; facc[0][1] = zz; facc[1][0] = zz; facc[1][1] = zz;
        #pragma unroll
        for (int ks = 0; ks < 4; ++ks) {     // all A prefetched
            int c0 = ks * 32 + quad * 8;
            short8 b0 = *(const short8*)(h_t + lq * 136 + c0);
            short8 b1 = *(const short8*)(h_t + (lq + 16) * 136 + c0);
            facc[0][0] = __builtin_amdgcn_mfma_f32_16x16x32_bf16(fa0[ks], b0, facc[0][0], 0, 0, 0);
            facc[0][1] = __builtin_amdgcn_mfma_f32_16x16x32_bf16(fa0[ks], b1, facc[0][1], 0, 0, 0);
            facc[1][0] = __builtin_amdgcn_mfma_f32_16x16x32_bf16(fa1[ks], b0, facc[1][0], 0, 0, 0);
            facc[1][1] = __builtin_amdgcn_mfma_f32_16x16x32_bf16(fa1[ks], b1, facc[1][1], 0, 0, 0);
        }
        const float inv = 0.08838834764831845f;   // 1/sqrt(128)
        #pragma unroll
        for (int mt = 0; mt < 2; ++mt) {
            int ob = wb + mt * 16 + quad * 4;
            float4 bb = *(const float4*)(bf2 + ob);
            float bv[4] = {bb.x, bb.y, bb.z, bb.w};
            float a0v[4], a1v[4];
            #pragma unroll
            for (int reg = 0; reg < 4; ++reg) {
                float v0 = facc[mt][0][reg] + bv[reg];
                float v1 = facc[mt][1][reg] + bv[reg];
                float mx = fmaxf(v0, v1);
                mx = fmaxf(mx, __shfl_xor(mx, 1));
                mx = fmaxf(mx, __shfl_xor(mx, 2));
                mx = fmaxf(mx, __shfl_xor(mx, 4));
                mx = fmaxf(mx, __shfl_xor(mx, 8));
                float e0 = __expf((v0 - mx) * inv);
                float e1 = __expf((v1 - mx) * inv);
                float sm = e0 + e1;
                sm += __shfl_xor(sm, 1);
                sm += __shfl_xor(sm, 2);
                sm += __shfl_xor(sm, 4);
                sm += __shfl_xor(sm, 8);
                float rs = 1.f / sm;
                a0v[reg] = e0 * rs;
                a1v[reg] = e1 * rs;
            }
            // transposed store: a_tT[o = ob+reg][s = lq / 16+lq]  (own wb rows)
            #pragma unroll
            for (int pr = 0; pr < 2; ++pr) {
                unsigned u0 = pk2(a0v[2 * pr], a0v[2 * pr + 1]);
                unsigned u1 = pk2(a1v[2 * pr], a1v[2 * pr + 1]);
                a_tt[(ob + 2 * pr)     * 40 + lq]      = (short)(u0 & 0xffff);
                a_tt[(ob + 2 * pr + 1) * 40 + lq]      = (short)(u0 >> 16);
                a_tt[(ob + 2 * pr)     * 40 + 16 + lq] = (short)(u1 & 0xffff);
                a_tt[(ob + 2 * pr + 1) * 40 + 16 + lq] = (short)(u1 >> 16);
            }
        }
    }
    // NO barrier: H reads a_tT rows of its OWN wb block (written by this wave),
    // fts (stable since B), xyz (stable); s_red region disjoint from h_t/a_tT.

    // ---------- Phase H: vv recomputed by MFMA from resident fts (Va prefetched);
    //            resi[i][d] = sum_s a[s][i] * (vv + pos), a via b64 from a_tT ----------
    {
        float pr[2][3];
        #pragma unroll
        for (int it = 0; it < 2; ++it)
            #pragma unroll
            for (int d = 0; d < 3; ++d) pr[it][d] = 0.f;
        #pragma unroll
        for (int mt = 0; mt < 6; ++mt) {
            int d  = mt >> 1;
            int s0 = (mt & 1) * 16 + quad * 4;
            const short* ap = fts_s + (mt * 16 + lq) * 72 + quad * 8;
            short8 a0 = *(const short8*)(ap);
            short8 a1 = *(const short8*)(ap + 32);
            #pragma unroll
            for (int it = 0; it < 2; ++it) {
                f32x4 vv = {0.f, 0.f, 0.f, 0.f};
                vv = __builtin_amdgcn_mfma_f32_16x16x32_bf16(a0, Va[it][0], vv, 0, 0, 0);
                vv = __builtin_amdgcn_mfma_f32_16x16x32_bf16(a1, Va[it][1], vv, 0, 0, 0);
                int i = wb + it * 16 + lq;
                uint2 av = *(const uint2*)(a_tt + i * 40 + s0);
                float aw[4] = { bf2f((short)(av.x & 0xffff)), bf2f((short)(av.x >> 16)),
                                bf2f((short)(av.y & 0xffff)), bf2f((short)(av.y >> 16)) };
                #pragma unroll
                for (int reg = 0; reg < 4; ++reg) {
                    int m = mt * 16 + quad * 4 + reg;      // == d*32 + s0 + reg
                    float vp = vv[reg] + wr2[it] * bf2f(s_xyzh[m]);
                    pr[it][d] = fmaf(aw[reg], vp, pr[it][d]);
                }
            }
        }
        #pragma unroll
        for (int it = 0; it < 2; ++it)
            #pragma unroll
            for (int d = 0; d < 3; ++d) {
                float v = pr[it][d];
                v += __shfl_xor(v, 16);
                v += __shfl_xor(v, 32);
                if (quad == 0) s_red[(wb + it * 16 + lq) * 3 + d] = v;
            }
    }
    LBAR();

    // write out: out[b][i][d][n], note i*3+d == e
    for (int e = t; e < 384; e += 256)
        out[(b * 384 + e) * NN + n] = s_red[e];
}

extern "C" void kernel_launch(void* const* d_in, const int* in_sizes, int n_in,
                              void* d_out, int out_size, void* d_ws, size_t ws_size,
                              hipStream_t stream) {
    const float* gxyz = (const float*)d_in[0];
    const float* gfts = (const float*)d_in[1];
    const float* qxyz = (const float*)d_in[2];
    const float* We1  = (const float*)d_in[3];
    const float* We2  = (const float*)d_in[4];
    const float* Wq   = (const float*)d_in[5];
    const float* Wk   = (const float*)d_in[6];
    const float* Wv   = (const float*)d_in[7];
    const float* Wr1  = (const float*)d_in[8];
    const float* Wr2  = (const float*)d_in[9];
    const float* Wstd = (const float*)d_in[10];
    const float* bf1  = (const float*)d_in[12];
    const float* bf2  = (const float*)d_in[14];
    float* out = (float*)d_out;
    float* ws  = (float*)d_ws;

    (void)hipFuncSetAttribute((const void*)fused_main,
                              hipFuncAttributeMaxDynamicSharedMemorySize, SMEM_BYTES);

    prep1<<<32, 256, 0, stream>>>(We1, We2, ws);
    prep2<<<353, 256, 0, stream>>>(Wq, Wk, Wv, Wr1, Wr2,
                                   (const float*)d_in[11], (const float*)d_in[13], ws);
    prep3<<<9, 256, 0, stream>>>(Wstd, ws);
    fused_main<<<BB * NN, 256, SMEM_BYTES, stream>>>(gxyz, gfts, qxyz, Wstd,
                                                     bf1, bf2, ws, out);
}

// Round 13
// 171.631 us; speedup vs baseline: 1.0174x; 1.0174x over previous
//
#include <hip/hip_runtime.h>
#include <hip/hip_bf16.h>
#include <math.h>

typedef __hip_bfloat16  bf16;
typedef __hip_bfloat162 bf162;
typedef __attribute__((ext_vector_type(8))) short short8;   // 8 bf16 (MFMA A/B frag)
typedef __attribute__((ext_vector_type(4))) float f32x4;    // MFMA C/D frag

#define BB   2
#define CINC 64
#define NN   1024
#define SSS  32
#define NS   (NN * SSS)

// ---- workspace layout (float offsets) ----
#define OFF_WE21 0        // f32 [o=128][c=64] (prep1/2); prep3 REUSES as WKA/wwr
#define OFF_WR   8192     // f32 [128]
#define OFF_KBA  8320     // bf16 [i=128][c2=128]: c2<64 -> Wk2 ; c2>=64 -> -Wq2
#define OFF_VB   16512    // bf16 [i=128][c=64]
#define OFF_F1B  20608    // bf16 [o=128][kappa=384], kappa=kk*128+i
#define OFF_F2B  45184    // bf16 [o=128][c=128]
// prep3 outputs: WKA bf16 [16][128] at OFF_WE21 ; wwr f32[3] at OFF_WE21+1024
#define WS_FLAG_IDX 2000
#define WS_MAGIC    0x5A17C0DEu
#define WS_NEED_FLOATS 53376

// ---- shared memory (BYTE offsets) ---- (40128 B, 4 blocks/CU)
#define S_ATT_B  0        // 26112 B
#define S_RED_B  18944    // f32[384] inside s_att free region
#define S_FTS_B  26112    // 96*72*2 = 13824 B (full tile staged in PROLOGUE)
#define S_XYZ_B  39936    // bf16[96] = 192 B
#define SMEM_BYTES 40128

// Light barrier (R11, measured -1.5%): barriers here guard LDS only, so wait
// lgkmcnt, not vmcnt -> pre-barrier GLOBAL loads stay in flight across it.
// R12 lesson: prefetch depth 2 is the sweet spot; depth 4+Va regressed
// (allocator reuses regs -> earlier vmcnt waits serialize the loads).
#define LBAR() do {                                         \
    asm volatile("s_waitcnt lgkmcnt(0)" ::: "memory");      \
    __builtin_amdgcn_s_barrier();                           \
    asm volatile("" ::: "memory");                          \
    __builtin_amdgcn_sched_barrier(0);                      \
} while (0)

__device__ __forceinline__ float bf2f(short s) {
    unsigned int u = ((unsigned int)(unsigned short)s) << 16;
    return __uint_as_float(u);
}
__device__ __forceinline__ short f2bf(float f) {
    bf16 h = __float2bfloat16(f);
    return *reinterpret_cast<short*>(&h);
}
__device__ __forceinline__ unsigned pk2(float a, float b) {
    bf162 p = __float22bfloat162_rn(make_float2(a, b));
    return *reinterpret_cast<unsigned*>(&p);
}
__device__ __forceinline__ bool prep_done(const float* ws) {
    return *(const volatile unsigned*)((const unsigned*)ws + WS_FLAG_IDX) == WS_MAGIC;
}

// ---------- prep kernel 1: We21 = W_e2 @ W_e1 ----------
__global__ __launch_bounds__(256) void prep1(const float* __restrict__ We1,
                                             const float* __restrict__ We2,
                                             float* __restrict__ ws) {
    if (prep_done(ws)) return;
    int e = blockIdx.x * 256 + threadIdx.x;   // 8192 entries, grid = 32
    int o = e >> 6, c = e & 63;
    float acc = 0.f;
    for (int m = 0; m < 128; ++m)
        acc = fmaf(We2[o * 128 + m], We1[m * 64 + c], acc);
    ws[OFF_WE21 + o * 64 + c] = acc;
}

// ---------- prep kernel 2: fused weights (KBA aug / VB / WR / F1B / F2B) ----------
__global__ __launch_bounds__(256) void prep2(const float* __restrict__ Wq,
                                             const float* __restrict__ Wk,
                                             const float* __restrict__ Wv,
                                             const float* __restrict__ Wr1,
                                             const float* __restrict__ Wr2,
                                             const float* __restrict__ Wf1,
                                             const float* __restrict__ Wf2,
                                             float* __restrict__ ws) {
    if (prep_done(ws)) return;
    const float* we21 = ws + OFF_WE21;
    int e = blockIdx.x * 256 + threadIdx.x;
    if (e < 16384) {                           // KBA bf16 [i][c2=128]
        int i = e >> 7, c2 = e & 127;
        const float* W = (c2 < 64) ? Wk : Wq;
        int c = c2 & 63;
        float acc = 0.f;
        for (int o = 0; o < 128; ++o)
            acc = fmaf(W[i * 128 + o], we21[o * 64 + c], acc);
        if (c2 >= 64) acc = -acc;
        ((bf16*)(ws + OFF_KBA))[i * 128 + c2] = __float2bfloat16(acc);
    } else if (e < 24576) {                    // VB bf16 [i][c=64]
        int le = e - 16384;
        int i = le >> 6, c = le & 63;
        float acc = 0.f;
        for (int o = 0; o < 128; ++o)
            acc = fmaf(Wv[i * 128 + o], we21[o * 64 + c], acc);
        ((bf16*)(ws + OFF_VB))[i * 64 + c] = __float2bfloat16(acc);
    } else if (e < 24704) {                    // w_r f32
        int i = e - 24576;
        float acc = 0.f;
        for (int m = 0; m < 64; ++m)
            acc = fmaf(Wr2[i * 64 + m], Wr1[m], acc);
        ws[OFF_WR + i] = acc;
    } else if (e < 24704 + 49152) {            // F1B[o][kappa], kappa = kk*128+i
        int f = e - 24704;
        int o = f / 384, kp = f - o * 384;
        int c = (kp & 127) * 3 + (kp >> 7);
        ((bf16*)(ws + OFF_F1B))[f] = __float2bfloat16(Wf1[o * 384 + c]);
    } else if (e < 24704 + 49152 + 16384) {    // F2B[o][c]
        int f = e - (24704 + 49152);
        ((bf16*)(ws + OFF_F2B))[f] = __float2bfloat16(Wf2[f]);
    }
}

// ---------- prep kernel 3: WKA = Wstd @ KBA (bf16), wwr = Wstd @ w_r ----------
__global__ __launch_bounds__(256) void prep3(const float* __restrict__ Wstd,
                                             float* __restrict__ ws) {
    if (prep_done(ws)) return;
    int e = blockIdx.x * 256 + threadIdx.x;
    if (e < 2048) {                            // WKA bf16 [16][128], rows>=3 zero
        int j = e >> 7, c2 = e & 127;
        float acc = 0.f;
        if (j < 3) {
            const short* kba = (const short*)(ws + OFF_KBA);
            for (int i = 0; i < 128; ++i)
                acc = fmaf(Wstd[j * 128 + i], bf2f(kba[i * 128 + c2]), acc);
        }
        ((bf16*)(ws + OFF_WE21))[e] = __float2bfloat16(acc);
    } else if (e < 2051) {                     // wwr f32[3]
        int j = e - 2048;
        float acc = 0.f;
        for (int i = 0; i < 128; ++i)
            acc = fmaf(Wstd[j * 128 + i], ws[OFF_WR + i], acc);
        ws[OFF_WE21 + 1024 + j] = acc;
        if (j == 0) {
            __threadfence();
            *(volatile unsigned*)((unsigned*)ws + WS_FLAG_IDX) = WS_MAGIC;
        }
    }
}

// ---------- main fused kernel: one block per (b, n) ----------
// FINAL (R11 structure, session best: fused ~60.8us, bench 172.9us):
//   - 4 blocks/CU at zero spills ((256,4), 40128B LDS, VGPR 56)
//   - phase C prep-fused (WKA); D wave-local; barriers 10 -> 6 (wave-locality)
//   - XCD-swizzled blockIdx -> output write-combining (WRITE 24.6 -> 3.07MB)
//   - light lgkmcnt-only barriers + 2-deep cross-barrier E/F A-frag prefetch
// R12 (4-deep prefetch + Va) regressed; reverted per pre-commitment.
__global__ __launch_bounds__(256, 4) void fused_main(
        const float* __restrict__ gxyz, const float* __restrict__ gfts,
        const float* __restrict__ qxyz, const float* __restrict__ Wstd,
        const float* __restrict__ bf1,  const float* __restrict__ bf2,
        const float* __restrict__ ws,   float* __restrict__ out) {
    extern __shared__ char smc[];
    short* s_att  = (short*)(smc + S_ATT_B);   // att_t[(kk*32+s)][136]
    short* h_t    = s_att;                     // alias [32][136] (post-E)
    short* a_tt   = s_att + 4352;              // alias: a_tT[o=128][stride 40] post-F
    short* fts_s  = (short*)(smc + S_FTS_B);   // [96][72] full tile, live A..H
    short* s_xyzh = (short*)(smc + S_XYZ_B);   // bf16 xyz_rel[96]
    float* s_red  = (float*)(smc + S_RED_B);   // H-reduction scratch (own region)

    const int t    = threadIdx.x;
    // XCD swizzle: consecutive n on one XCD -> output write-combining in its L2
    const int bid0 = blockIdx.x;
    const int bid  = ((bid0 & 7) << 8) | (bid0 >> 3);   // bijective on 2048
    const int b    = bid >> 10;
    const int n    = bid & 1023;
    const int w    = t >> 6;        // wave id 0..3
    const int lane = t & 63;
    const int quad = lane >> 4;
    const int lq   = lane & 15;
    const int wb   = 32 * w;        // wave's i-base (B,H) / o-base (E,F)

    const float* gb = gfts + (size_t)b * (CINC * 3 * NS) + n * SSS;
    const short* kba = (const short*)(ws + OFF_KBA);
    const short* wka = (const short*)(ws + OFF_WE21);

    // staging geometry
    const int cp = t >> 3;              // c-pair 0..31
    const int ml = (t & 7) * 4;         // s base 0,4,...,28

    // ---------- persistent fragments: Ka + kq (h-invariant) + w_r + WKA ----------
    short8 Ka[2][2], Kq[2][2];
    #pragma unroll
    for (int it = 0; it < 2; ++it) {
        int i = wb + it * 16 + lq;
        Ka[it][0] = *(const short8*)(kba + i * 128 +  0 + quad * 8);
        Ka[it][1] = *(const short8*)(kba + i * 128 + 32 + quad * 8);
        Kq[it][0] = *(const short8*)(kba + i * 128 + 64 + quad * 8);
        Kq[it][1] = *(const short8*)(kba + i * 128 + 96 + quad * 8);
    }
    float4 wr2v[2] = { *(const float4*)(ws + OFF_WR + wb + quad * 4),
                       *(const float4*)(ws + OFF_WR + wb + 16 + quad * 4) };
    float wr2[2] = { ws[OFF_WR + wb + lq], ws[OFF_WR + wb + 16 + lq] };
    short8 WA[4];
    float wwr[3];
    if (w >= 2) {                       // only waves 2,3 compute z0
        #pragma unroll
        for (int kc = 0; kc < 4; ++kc)
            WA[kc] = *(const short8*)(wka + lq * 128 + kc * 32 + quad * 8);
        wwr[0] = ws[OFF_WE21 + 1024];
        wwr[1] = ws[OFF_WE21 + 1025];
        wwr[2] = ws[OFF_WE21 + 1026];
    }

    // ---------- PROLOGUE: stage ALL thirds (6 parallel float4 loads) + xyz ----------
    {
        float4 g0[3], g1[3];
        #pragma unroll
        for (int h = 0; h < 3; ++h) {
            const float* fb = gb + (2 * cp * 3 + h) * NS + ml;
            g0[h] = *(const float4*)(fb);
            g1[h] = *(const float4*)(fb + 3 * NS);
        }
        #pragma unroll
        for (int h = 0; h < 3; ++h) {
            short* dst = fts_s + (h * 32 + ml) * 72 + 2 * cp;
            *(unsigned*)(dst)       = pk2(g0[h].x, g1[h].x);
            *(unsigned*)(dst + 72)  = pk2(g0[h].y, g1[h].y);
            *(unsigned*)(dst + 144) = pk2(g0[h].z, g1[h].z);
            *(unsigned*)(dst + 216) = pk2(g0[h].w, g1[h].w);
        }
        if (t >= 160) {
            int id = t - 160;                // 0..95
            int d = id >> 5, s = id & 31;
            s_xyzh[id] = f2bf(gxyz[((b * NN + n) * SSS + s) * 3 + d]
                              - qxyz[(b * NN + n) * 3 + d]);
        }
    }
    LBAR();

    // ---------- Phase B: barrier-free (fts stable; att cols + z0 holes wave-owned) ----------
    #pragma unroll
    for (int h = 0; h < 3; ++h) {
        const short* qp = fts_s + (h * 32) * 72 + quad * 8;
        short8 aq0 = *(const short8*)(qp);
        short8 aq1 = *(const short8*)(qp + 32);

        // qv[it][reg] = -q[i] via swapped MFMA (B cols all = q row h*32)
        f32x4 qa[2];
        #pragma unroll
        for (int it = 0; it < 2; ++it) {
            f32x4 z = {0.f, 0.f, 0.f, 0.f};
            z = __builtin_amdgcn_mfma_f32_16x16x32_bf16(Kq[it][0], aq0, z, 0, 0, 0);
            z = __builtin_amdgcn_mfma_f32_16x16x32_bf16(Kq[it][1], aq1, z, 0, 0, 0);
            qa[it] = z;
        }
        #pragma unroll
        for (int mt_h = 0; mt_h < 2; ++mt_h) {
            int m = h * 32 + mt_h * 16 + lq;         // att row (= output col)
            const short* ap = fts_s + m * 72 + quad * 8;
            short8 a0 = *(const short8*)(ap);
            short8 a1 = *(const short8*)(ap + 32);
            float xm = bf2f(s_xyzh[m]);
            #pragma unroll
            for (int it = 0; it < 2; ++it) {
                f32x4 kk = {0.f, 0.f, 0.f, 0.f};
                kk = __builtin_amdgcn_mfma_f32_16x16x32_bf16(Ka[it][0], a0, kk, 0, 0, 0);
                kk = __builtin_amdgcn_mfma_f32_16x16x32_bf16(Ka[it][1], a1, kk, 0, 0, 0);
                float p[4];
                #pragma unroll
                for (int reg = 0; reg < 4; ++reg)
                    p[reg] = wr2v[it][reg] * xm - kk[reg] - qa[it][reg];
                uint2 pk;
                pk.x = pk2(p[0], p[1]);
                pk.y = pk2(p[2], p[3]);
                *(uint2*)(s_att + m * 136 + wb + it * 16 + quad * 4) = pk;
            }
            // z0[j][m] = xm*wwr[j] - sum_c WKA[j][c2]*(fts|ftsq)[c2]  (fused C)
            if (w == 2 + mt_h) {
                f32x4 z2 = {0.f, 0.f, 0.f, 0.f};
                z2 = __builtin_amdgcn_mfma_f32_16x16x32_bf16(WA[0], a0,  z2, 0, 0, 0);
                z2 = __builtin_amdgcn_mfma_f32_16x16x32_bf16(WA[1], a1,  z2, 0, 0, 0);
                z2 = __builtin_amdgcn_mfma_f32_16x16x32_bf16(WA[2], aq0, z2, 0, 0, 0);
                z2 = __builtin_amdgcn_mfma_f32_16x16x32_bf16(WA[3], aq1, z2, 0, 0, 0);
                if (quad == 0) {          // rows j = reg < 3 ; col m = this lane's m
                    float* hp = (float*)(fts_s + m * 72 + 64);
                    #pragma unroll
                    for (int reg = 0; reg < 3; ++reg)
                        hp[reg] = xm * wwr[reg] - z2[reg];
                }
            }
        }
    }
    LBAR();   // publishes att (all cols) + z0 holes

    // ---------- Phase D (wave-local i-cols): attn2[i][kk][s] = sum_j att*z0 ----------
    #pragma unroll
    for (int u2 = 0; u2 < 2; ++u2) {
        int item = u2 * 64 + lane;
        int s  = item & 31;
        int i0 = wb + (item >> 5) * 8;        // own wave's columns only
        float z[3][3];
        #pragma unroll
        for (int kk = 0; kk < 3; ++kk) {
            const float* hp = (const float*)(fts_s + (kk * 32 + s) * 72 + 64);
            #pragma unroll
            for (int j = 0; j < 3; ++j)
                z[j][kk] = hp[j];
        }
        float af[3][8];
        #pragma unroll
        for (int j = 0; j < 3; ++j) {
            short8 v8 = *(const short8*)(s_att + (j * 32 + s) * 136 + i0);
            #pragma unroll
            for (int x = 0; x < 8; ++x) af[j][x] = bf2f(v8[x]);
        }
        #pragma unroll
        for (int kk = 0; kk < 3; ++kk) {
            float q0, q1;
            uint4 o4;
            q0 = af[0][0] * z[0][kk] + af[1][0] * z[1][kk] + af[2][0] * z[2][kk];
            q1 = af[0][1] * z[0][kk] + af[1][1] * z[1][kk] + af[2][1] * z[2][kk];
            o4.x = pk2(q0, q1);
            q0 = af[0][2] * z[0][kk] + af[1][2] * z[1][kk] + af[2][2] * z[2][kk];
            q1 = af[0][3] * z[0][kk] + af[1][3] * z[1][kk] + af[2][3] * z[2][kk];
            o4.y = pk2(q0, q1);
            q0 = af[0][4] * z[0][kk] + af[1][4] * z[1][kk] + af[2][4] * z[2][kk];
            q1 = af[0][5] * z[0][kk] + af[1][5] * z[1][kk] + af[2][5] * z[2][kk];
            o4.z = pk2(q0, q1);
            q0 = af[0][6] * z[0][kk] + af[1][6] * z[1][kk] + af[2][6] * z[2][kk];
            q1 = af[0][7] * z[0][kk] + af[1][7] * z[1][kk] + af[2][7] * z[2][kk];
            o4.w = pk2(q0, q1);
            *(uint4*)(s_att + (kk * 32 + s) * 136 + i0) = o4;
        }
    }
    // Prefetch E's first two A-frag pairs (global, L2-hot ws) BEFORE the
    // light barrier -> loads stay in flight across it.
    const short* f1b  = (const short*)(ws + OFF_F1B);
    const short* eab0 = f1b + (wb + lq) * 384 + quad * 8;
    const short* eab1 = eab0 + 16 * 384;
    short8 ea00 = *(const short8*)(eab0);
    short8 ea10 = *(const short8*)(eab1);
    short8 ea01 = *(const short8*)(eab0 + 32);
    short8 ea11 = *(const short8*)(eab1 + 32);
    LBAR();

    // ---------- Phase E: h = relu(Wf1 @ attn2 + b_f1) via MFMA (M=128,N=32,K=384) ----------
    f32x4 eacc[2][2];
    {
        f32x4 zz = {0.f, 0.f, 0.f, 0.f};
        eacc[0][0] = zz; eacc[0][1] = zz; eacc[1][0] = zz; eacc[1][1] = zz;
        {   // ks = 0 (kk=0, ic=quad*8) -- prefetched A
            const short* bp = s_att + quad * 8;
            short8 b0 = *(const short8*)(bp + lq * 136);
            short8 b1 = *(const short8*)(bp + (lq + 16) * 136);
            eacc[0][0] = __builtin_amdgcn_mfma_f32_16x16x32_bf16(ea00, b0, eacc[0][0], 0, 0, 0);
            eacc[0][1] = __builtin_amdgcn_mfma_f32_16x16x32_bf16(ea00, b1, eacc[0][1], 0, 0, 0);
            eacc[1][0] = __builtin_amdgcn_mfma_f32_16x16x32_bf16(ea10, b0, eacc[1][0], 0, 0, 0);
            eacc[1][1] = __builtin_amdgcn_mfma_f32_16x16x32_bf16(ea10, b1, eacc[1][1], 0, 0, 0);
        }
        {   // ks = 1 (kk=0, ic=32+quad*8) -- prefetched A
            const short* bp = s_att + 32 + quad * 8;
            short8 b0 = *(const short8*)(bp + lq * 136);
            short8 b1 = *(const short8*)(bp + (lq + 16) * 136);
            eacc[0][0] = __builtin_amdgcn_mfma_f32_16x16x32_bf16(ea01, b0, eacc[0][0], 0, 0, 0);
            eacc[0][1] = __builtin_amdgcn_mfma_f32_16x16x32_bf16(ea01, b1, eacc[0][1], 0, 0, 0);
            eacc[1][0] = __builtin_amdgcn_mfma_f32_16x16x32_bf16(ea11, b0, eacc[1][0], 0, 0, 0);
            eacc[1][1] = __builtin_amdgcn_mfma_f32_16x16x32_bf16(ea11, b1, eacc[1][1], 0, 0, 0);
        }
        #pragma unroll 2
        for (int ks = 2; ks < 12; ++ks) {
            int kk = ks >> 2;
            int ic = (ks & 3) * 32 + quad * 8;
            short8 a0 = *(const short8*)(eab0 + ks * 32);
            short8 a1 = *(const short8*)(eab1 + ks * 32);
            const short* bp = s_att + (kk * 32) * 136 + ic;
            short8 b0 = *(const short8*)(bp + lq * 136);
            short8 b1 = *(const short8*)(bp + (lq + 16) * 136);
            eacc[0][0] = __builtin_amdgcn_mfma_f32_16x16x32_bf16(a0, b0, eacc[0][0], 0, 0, 0);
            eacc[0][1] = __builtin_amdgcn_mfma_f32_16x16x32_bf16(a0, b1, eacc[0][1], 0, 0, 0);
            eacc[1][0] = __builtin_amdgcn_mfma_f32_16x16x32_bf16(a1, b0, eacc[1][0], 0, 0, 0);
            eacc[1][1] = __builtin_amdgcn_mfma_f32_16x16x32_bf16(a1, b1, eacc[1][1], 0, 0, 0);
        }
    }
    LBAR();     // all attn2 reads complete before h_t overwrites it

    // E epilogue: h_t[s][o] (bf16), relu+bias
    #pragma unroll
    for (int mt = 0; mt < 2; ++mt) {
        int ob = wb + mt * 16 + quad * 4;
        float4 bb = *(const float4*)(bf1 + ob);
        float bv[4] = {bb.x, bb.y, bb.z, bb.w};
        #pragma unroll
        for (int nt = 0; nt < 2; ++nt) {
            f32x4 c = eacc[mt][nt];
            int s = nt * 16 + lq;
            uint2 pk;
            pk.x = pk2(fmaxf(c[0] + bv[0], 0.f), fmaxf(c[1] + bv[1], 0.f));
            pk.y = pk2(fmaxf(c[2] + bv[2], 0.f), fmaxf(c[3] + bv[3], 0.f));
            *(uint2*)(h_t + s * 136 + ob) = pk;
        }
    }
    // Prefetch F's first two A-frag pairs BEFORE the light barrier.
    const short* f2b  = (const short*)(ws + OFF_F2B);
    const short* fab0 = f2b + (wb + lq) * 128 + quad * 8;
    const short* fab1 = fab0 + 16 * 128;
    short8 fa00 = *(const short8*)(fab0);
    short8 fa10 = *(const short8*)(fab1);
    short8 fa01 = *(const short8*)(fab0 + 32);
    short8 fa11 = *(const short8*)(fab1 + 32);
    LBAR();

    // ---------- Phase F: logits + FUSED SOFTMAX; store TRANSPOSED a_tT[o][40] ----------
    {
        f32x4 facc[2][2];
        f32x4 zz = {0.f, 0.f, 0.f, 0.f};
        facc[0][0] = zz; facc[0][1] = zz; facc[1][0] = zz; facc[1][1] = zz;
        {   // ks = 0 (c0 = quad*8) -- prefetched A
            short8 b0 = *(const short8*)(h_t + lq * 136 + quad * 8);
            short8 b1 = *(const short8*)(h_t + (lq + 16) * 136 + quad * 8);
            facc[0][0] = __builtin_amdgcn_mfma_f32_16x16x32_bf16(fa00, b0, facc[0][0], 0, 0, 0);
            facc[0][1] = __builtin_amdgcn_mfma_f32_16x16x32_bf16(fa00, b1, facc[0][1], 0, 0, 0);
            facc[1][0] = __builtin_amdgcn_mfma_f32_16x16x32_bf16(fa10, b0, facc[1][0], 0, 0, 0);
            facc[1][1] = __builtin_amdgcn_mfma_f32_16x16x32_bf16(fa10, b1, facc[1][1], 0, 0, 0);
        }
        {   // ks = 1 (c0 = 32+quad*8) -- prefetched A
            short8 b0 = *(const short8*)(h_t + lq * 136 + 32 + quad * 8);
            short8 b1 = *(const short8*)(h_t + (lq + 16) * 136 + 32 + quad * 8);
            facc[0][0] = __builtin_amdgcn_mfma_f32_16x16x32_bf16(fa01, b0, facc[0][0], 0, 0, 0);
            facc[0][1] = __builtin_amdgcn_mfma_f32_16x16x32_bf16(fa01, b1, facc[0][1], 0, 0, 0);
            facc[1][0] = __builtin_amdgcn_mfma_f32_16x16x32_bf16(fa11, b0, facc[1][0], 0, 0, 0);
            facc[1][1] = __builtin_amdgcn_mfma_f32_16x16x32_bf16(fa11, b1, facc[1][1], 0, 0, 0);
        }
        #pragma unroll
        for (int ks = 2; ks < 4; ++ks) {
            int c0 = ks * 32 + quad * 8;
            short8 a0 = *(const short8*)(fab0 + ks * 32);
            short8 a1 = *(const short8*)(fab1 + ks * 32);
            short8 b0 = *(const short8*)(h_t + lq * 136 + c0);
            short8 b1 = *(const short8*)(h_t + (lq + 16) * 136 + c0);
            facc[0][0] = __builtin_amdgcn_mfma_f32_16x16x32_bf16(a0, b0, facc[0][0], 0, 0, 0);
            facc[0][1] = __builtin_amdgcn_mfma_f32_16x16x32_bf16(a0, b1, facc[0][1], 0, 0, 0);
            facc[1][0] = __builtin_amdgcn_mfma_f32_16x16x32_bf16(a1, b0, facc[1][0], 0, 0, 0);
            facc[1][1] = __builtin_amdgcn_mfma_f32_16x16x32_bf16(a1, b1, facc[1][1], 0, 0, 0);
        }
        const float inv = 0.08838834764831845f;   // 1/sqrt(128)
        #pragma unroll
        for (int mt = 0; mt < 2; ++mt) {
            int ob = wb + mt * 16 + quad * 4;
            float4 bb = *(const float4*)(bf2 + ob);
            float bv[4] = {bb.x, bb.y, bb.z, bb.w};
            float a0v[4], a1v[4];
            #pragma unroll
            for (int reg = 0; reg < 4; ++reg) {
                float v0 = facc[mt][0][reg] + bv[reg];
                float v1 = facc[mt][1][reg] + bv[reg];
                float mx = fmaxf(v0, v1);
                mx = fmaxf(mx, __shfl_xor(mx, 1));
                mx = fmaxf(mx, __shfl_xor(mx, 2));
                mx = fmaxf(mx, __shfl_xor(mx, 4));
                mx = fmaxf(mx, __shfl_xor(mx, 8));
                float e0 = __expf((v0 - mx) * inv);
                float e1 = __expf((v1 - mx) * inv);
                float sm = e0 + e1;
                sm += __shfl_xor(sm, 1);
                sm += __shfl_xor(sm, 2);
                sm += __shfl_xor(sm, 4);
                sm += __shfl_xor(sm, 8);
                float rs = 1.f / sm;
                a0v[reg] = e0 * rs;
                a1v[reg] = e1 * rs;
            }
            // transposed store: a_tT[o = ob+reg][s = lq / 16+lq]  (own wb rows)
            #pragma unroll
            for (int pr = 0; pr < 2; ++pr) {
                unsigned u0 = pk2(a0v[2 * pr], a0v[2 * pr + 1]);
                unsigned u1 = pk2(a1v[2 * pr], a1v[2 * pr + 1]);
                a_tt[(ob + 2 * pr)     * 40 + lq]      = (short)(u0 & 0xffff);
                a_tt[(ob + 2 * pr + 1) * 40 + lq]      = (short)(u0 >> 16);
                a_tt[(ob + 2 * pr)     * 40 + 16 + lq] = (short)(u1 & 0xffff);
                a_tt[(ob + 2 * pr + 1) * 40 + 16 + lq] = (short)(u1 >> 16);
            }
        }
    }
    // NO barrier: H reads a_tT rows of its OWN wb block (written by this wave),
    // fts (stable since B), xyz (stable); s_red region disjoint from h_t/a_tT.

    // ---------- Phase H: vv recomputed by MFMA from resident fts; then
    //            resi[i][d] = sum_s a[s][i] * (vv + pos), a via b64 from a_tT ----------
    {
        short8 Va[2][2];
        {
            const short* vbb = (const short*)(ws + OFF_VB);
            #pragma unroll
            for (int it = 0; it < 2; ++it) {
                int i = wb + it * 16 + lq;
                #pragma unroll
                for (int kc = 0; kc < 2; ++kc)
                    Va[it][kc] = *(const short8*)(vbb + i * 64 + kc * 32 + quad * 8);
            }
        }
        float pr[2][3];
        #pragma unroll
        for (int it = 0; it < 2; ++it)
            #pragma unroll
            for (int d = 0; d < 3; ++d) pr[it][d] = 0.f;
        #pragma unroll
        for (int mt = 0; mt < 6; ++mt) {
            int d  = mt >> 1;
            int s0 = (mt & 1) * 16 + quad * 4;
            const short* ap = fts_s + (mt * 16 + lq) * 72 + quad * 8;
            short8 a0 = *(const short8*)(ap);
            short8 a1 = *(const short8*)(ap + 32);
            #pragma unroll
            for (int it = 0; it < 2; ++it) {
                f32x4 vv = {0.f, 0.f, 0.f, 0.f};
                vv = __builtin_amdgcn_mfma_f32_16x16x32_bf16(a0, Va[it][0], vv, 0, 0, 0);
                vv = __builtin_amdgcn_mfma_f32_16x16x32_bf16(a1, Va[it][1], vv, 0, 0, 0);
                int i = wb + it * 16 + lq;
                uint2 av = *(const uint2*)(a_tt + i * 40 + s0);
                float aw[4] = { bf2f((short)(av.x & 0xffff)), bf2f((short)(av.x >> 16)),
                                bf2f((short)(av.y & 0xffff)), bf2f((short)(av.y >> 16)) };
                #pragma unroll
                for (int reg = 0; reg < 4; ++reg) {
                    int m = mt * 16 + quad * 4 + reg;      // == d*32 + s0 + reg
                    float vp = vv[reg] + wr2[it] * bf2f(s_xyzh[m]);
                    pr[it][d] = fmaf(aw[reg], vp, pr[it][d]);
                }
            }
        }
        #pragma unroll
        for (int it = 0; it < 2; ++it)
            #pragma unroll
            for (int d = 0; d < 3; ++d) {
                float v = pr[it][d];
                v += __shfl_xor(v, 16);
                v += __shfl_xor(v, 32);
                if (quad == 0) s_red[(wb + it * 16 + lq) * 3 + d] = v;
            }
    }
    LBAR();

    // write out: out[b][i][d][n], note i*3+d == e
    for (int e = t; e < 384; e += 256)
        out[(b * 384 + e) * NN + n] = s_red[e];
}

extern "C" void kernel_launch(void* const* d_in, const int* in_sizes, int n_in,
                              void* d_out, int out_size, void* d_ws, size_t ws_size,
                              hipStream_t stream) {
    const float* gxyz = (const float*)d_in[0];
    const float* gfts = (const float*)d_in[1];
    const float* qxyz = (const float*)d_in[2];
    const float* We1  = (const float*)d_in[3];
    const float* We2  = (const float*)d_in[4];
    const float* Wq   = (const float*)d_in[5];
    const float* Wk   = (const float*)d_in[6];
    const float* Wv   = (const float*)d_in[7];
    const float* Wr1  = (const float*)d_in[8];
    const float* Wr2  = (const float*)d_in[9];
    const float* Wstd = (const float*)d_in[10];
    const float* bf1  = (const float*)d_in[12];
    const float* bf2  = (const float*)d_in[14];
    float* out = (float*)d_out;
    float* ws  = (float*)d_ws;

    (void)hipFuncSetAttribute((const void*)fused_main,
                              hipFuncAttributeMaxDynamicSharedMemorySize, SMEM_BYTES);

    prep1<<<32, 256, 0, stream>>>(We1, We2, ws);
    prep2<<<353, 256, 0, stream>>>(Wq, Wk, Wv, Wr1, Wr2,
                                   (const float*)d_in[11], (const float*)d_in[13], ws);
    prep3<<<9, 256, 0, stream>>>(Wstd, ws);
    fused_main<<<BB * NN, 256, SMEM_BYTES, stream>>>(gxyz, gfts, qxyz, Wstd,
                                                     bf1, bf2, ws, out);
}